// Round 2
// baseline (2118.245 us; speedup 1.0000x reference)
//
#include <hip/hip_runtime.h>
#include <hip/hip_bf16.h>

#define B_   8
#define C_   512
#define HW_  4096
#define M_   1024
#define N_   3072
#define EPS_ 1e-8f

#define KCH   16
#define NTILE 512

// ---------------- K1: per-column inverse norms (all 4096 columns) ----------
__global__ void k_norms(const float* __restrict__ x, float* __restrict__ inv_all) {
    int blk = blockIdx.x;            // 256 blocks = 8 b * 32 chunks
    int b = blk >> 5;
    int chunk = blk & 31;
    int hw = chunk * 128 + threadIdx.x;   // 128 threads
    const float* xb = x + (size_t)b * C_ * HW_;
    float acc = 0.f;
#pragma unroll 8
    for (int c = 0; c < C_; ++c) {
        float v = xb[(size_t)c * HW_ + hw];
        acc = fmaf(v, v, acc);
    }
    inv_all[b * HW_ + hw] = 1.0f / (sqrtf(acc) + EPS_);
}

// ---------------- K2: cos-sim GEMM + per-row top-2 ------------------------
// grid = 512 blocks: b(8) x mtile(32, 32 rows each) x nsplit(2, 1536 each)
// block = 256 threads = 4 tm x 64 tn ; microtile 8m x 8n ; tile 32m x 512n
__global__ __launch_bounds__(256, 2) void k_cos(
    const float* __restrict__ x, const int* __restrict__ nm_idx,
    const int* __restrict__ m_idx, const float* __restrict__ inv_all,
    float* __restrict__ pmax, int* __restrict__ pidx)
{
    __shared__ float As[KCH][32];
    __shared__ float Bs[KCH][NTILE];
    __shared__ int   nsp[NTILE];
    __shared__ float invc[NTILE];
    __shared__ int   ps[32];
    __shared__ float invm[32];

    int blk = blockIdx.x;
    int b     = blk >> 6;
    int mt    = (blk >> 1) & 31;
    int split = blk & 1;
    int m0 = mt * 32;
    int t  = threadIdx.x;
    int tn = t & 63;
    int tm = t >> 6;

    const float* xb   = x + (size_t)b * C_ * HW_;
    const float* invb = inv_all + b * HW_;

    if (t < 32) {
        int p = m_idx[m0 + t];
        ps[t] = p;
        invm[t] = invb[p];
    }

    float v1[8], v2[8]; int i1[8], i2[8];
#pragma unroll
    for (int mi = 0; mi < 8; ++mi) {
        v1[mi] = -3.402823466e38f; v2[mi] = -3.402823466e38f;
        i1[mi] = 0x7fffffff;       i2[mi] = 0x7fffffff;
    }

    int nbase = split * 1536;
    for (int nt = 0; nt < 1536; nt += NTILE) {
        __syncthreads();   // protect nsp/invc (and ps/invm on first pass)
        {
            int j = t;
            int p = nm_idx[nbase + nt + j];
            nsp[j] = p; invc[j] = invb[p];
            j = t + 256;
            p = nm_idx[nbase + nt + j];
            nsp[j] = p; invc[j] = invb[p];
        }
        __syncthreads();

        float acc[8][8];
#pragma unroll
        for (int a = 0; a < 8; ++a)
#pragma unroll
            for (int q = 0; q < 8; ++q) acc[a][q] = 0.f;

        for (int k0 = 0; k0 < C_; k0 += KCH) {
            // stage A: 16k x 32m
            {
                int idx = t;
                int kk = idx >> 5, i = idx & 31;
                As[kk][i] = xb[(size_t)(k0 + kk) * HW_ + ps[i]];
                idx = t + 256; kk = idx >> 5; i = idx & 31;
                As[kk][i] = xb[(size_t)(k0 + kk) * HW_ + ps[i]];
            }
            // stage B: 16k x 512n
#pragma unroll
            for (int rep = 0; rep < 32; ++rep) {
                int idx = rep * 256 + t;
                int kk = idx >> 9, j = idx & 511;
                Bs[kk][j] = xb[(size_t)(k0 + kk) * HW_ + nsp[j]];
            }
            __syncthreads();
#pragma unroll
            for (int kk = 0; kk < KCH; ++kk) {
                float a[8], bb[8];
                *(float4*)&a[0]  = *(const float4*)&As[kk][tm * 8];
                *(float4*)&a[4]  = *(const float4*)&As[kk][tm * 8 + 4];
                *(float4*)&bb[0] = *(const float4*)&Bs[kk][tn * 4];
                *(float4*)&bb[4] = *(const float4*)&Bs[kk][256 + tn * 4];
#pragma unroll
                for (int mi = 0; mi < 8; ++mi)
#pragma unroll
                    for (int nj = 0; nj < 8; ++nj)
                        acc[mi][nj] = fmaf(a[mi], bb[nj], acc[mi][nj]);
            }
            __syncthreads();
        }
        // epilogue: scale to cosine, insert into top-2
#pragma unroll
        for (int mi = 0; mi < 8; ++mi) {
            float im = invm[tm * 8 + mi];
#pragma unroll
            for (int nj = 0; nj < 8; ++nj) {
                int jl = (nj < 4) ? (tn * 4 + nj) : (256 + tn * 4 + nj - 4);
                float v = acc[mi][nj] * im * invc[jl];
                int n = nbase + nt + jl;
                if (v > v1[mi] || (v == v1[mi] && n < i1[mi])) {
                    v2[mi] = v1[mi]; i2[mi] = i1[mi]; v1[mi] = v; i1[mi] = n;
                } else if (v > v2[mi] || (v == v2[mi] && n < i2[mi])) {
                    v2[mi] = v; i2[mi] = n;
                }
            }
        }
    }

    // wave butterfly top-2 reduction (each wave == one tm, covers 8 m's)
#pragma unroll
    for (int mi = 0; mi < 8; ++mi) {
        float a1v = v1[mi], a2v = v2[mi]; int a1i = i1[mi], a2i = i2[mi];
        for (int off = 32; off; off >>= 1) {
            float o1v = __shfl_xor(a1v, off, 64); int o1i = __shfl_xor(a1i, off, 64);
            float o2v = __shfl_xor(a2v, off, 64); int o2i = __shfl_xor(a2i, off, 64);
            if (o1v > a1v || (o1v == a1v && o1i < a1i)) { a2v = a1v; a2i = a1i; a1v = o1v; a1i = o1i; }
            else if (o1v > a2v || (o1v == a2v && o1i < a2i)) { a2v = o1v; a2i = o1i; }
            if (o2v > a1v || (o2v == a1v && o2i < a1i)) { a2v = a1v; a2i = a1i; a1v = o2v; a1i = o2i; }
            else if (o2v > a2v || (o2v == a2v && o2i < a2i)) { a2v = o2v; a2i = o2i; }
        }
        if (tn == 0) {
            int m = m0 + tm * 8 + mi;
            int id = (b << 10) + m;
            int o = id * 4 + split * 2;     // [id][split][rank]
            pmax[o + 0] = a1v; pidx[o + 0] = a1i;
            pmax[o + 1] = a2v; pidx[o + 1] = a2i;
        }
    }
}

// ---------------- K3: combine splits + fp64 re-check near-ties -------------
__global__ void k_combine(const float* __restrict__ x,
    const int* __restrict__ nm_idx, const int* __restrict__ m_idx,
    const float* __restrict__ pmax, const int* __restrict__ pidx,
    float* __restrict__ maxc, int* __restrict__ bestp)
{
    int id = blockIdx.x * 256 + threadIdx.x;     // 8192
    int b = id >> 10, m = id & 1023;
    float v1 = -3.402823466e38f, v2 = -3.402823466e38f;
    int i1 = 0x7fffffff, i2 = 0x7fffffff;
#pragma unroll
    for (int r = 0; r < 4; ++r) {
        float v = pmax[id * 4 + r];
        int   n = pidx[id * 4 + r];
        if (v > v1 || (v == v1 && n < i1)) { v2 = v1; i2 = i1; v1 = v; i1 = n; }
        else if (v > v2 || (v == v2 && n < i2)) { v2 = v; i2 = n; }
    }
    if (v1 - v2 < 1e-5f) {
        // exact fp64 decision between the two candidates
        const float* xb = x + (size_t)b * C_ * HW_;
        int pm = m_idx[m], p1 = nm_idx[i1], p2 = nm_idx[i2];
        double smm = 0, s11 = 0, s22 = 0, sm1 = 0, sm2 = 0;
        for (int c = 0; c < C_; ++c) {
            double xm = xb[(size_t)c * HW_ + pm];
            double xa = xb[(size_t)c * HW_ + p1];
            double xc = xb[(size_t)c * HW_ + p2];
            smm += xm * xm; s11 += xa * xa; s22 += xc * xc;
            sm1 += xm * xa; sm2 += xm * xc;
        }
        double inv_m = 1.0 / (sqrt(smm) + 1e-8);
        double c1 = sm1 * inv_m / (sqrt(s11) + 1e-8);
        double c2 = sm2 * inv_m / (sqrt(s22) + 1e-8);
        if (c2 > c1 || (c2 == c1 && i2 < i1)) { v1 = v2; i1 = i2; }
    }
    maxc[id]  = v1;
    bestp[id] = nm_idx[i1];
}

// ---------------- K4: copy input -> output (context passthrough) -----------
__global__ void k_copy(const float4* __restrict__ in, float4* __restrict__ out) {
    int idx = blockIdx.x * 256 + threadIdx.x;
    int stride = gridDim.x * 256;
    for (int i = idx; i < (B_ * C_ * HW_ / 4); i += stride) out[i] = in[i];
}

// ---------------- K5: gather dense msk_n and best buffers ------------------
// grid = 256 blocks: b(8) x hole-row(32); block = 256 threads
__global__ __launch_bounds__(256) void k_gather(const float* __restrict__ x,
    const int* __restrict__ m_idx, const float* __restrict__ inv_all,
    const int* __restrict__ bestp, float* __restrict__ mskn, float* __restrict__ best)
{
    __shared__ float T[32][513];
    __shared__ int ps[32]; __shared__ float invm[32]; __shared__ int bp[32];
    int blk = blockIdx.x;
    int b = blk >> 5, row = blk & 31;
    int m0 = row * 32;
    int t = threadIdx.x;
    const float* xb = x + (size_t)b * C_ * HW_;
    if (t < 32) {
        int p = m_idx[m0 + t];
        ps[t] = p; invm[t] = inv_all[b * HW_ + p];
        bp[t] = bestp[(b << 10) + m0 + t];
    }
    __syncthreads();
    // transpose-load mask features: x[b][c][p_i] -> T[i][c]
#pragma unroll 4
    for (int rep = 0; rep < 64; ++rep) {
        int idx = rep * 256 + t;
        int c = idx >> 5, i = idx & 31;
        T[i][c] = xb[(size_t)c * HW_ + ps[i]];
    }
    __syncthreads();
#pragma unroll 4
    for (int rep = 0; rep < 64; ++rep) {
        int idx = rep * 256 + t;
        int i = idx >> 9, c = idx & 511;
        mskn[((size_t)(b << 10) + m0 + i) * C_ + c] = T[i][c] * invm[i];
    }
    // best: scattered reads, coalesced writes
    for (int mi = 0; mi < 32; ++mi) {
        int p = bp[mi];
        size_t o = ((size_t)(b << 10) + m0 + mi) * C_;
        for (int c = t; c < C_; c += 256)
            best[o + c] = xb[(size_t)c * HW_ + p];
    }
}

// ---------------- DPP wave-64 sum: result broadcast via readlane(63) -------
__device__ __forceinline__ float wave_sum64(float x) {
    // row_shr 1,2,4,8 within 16-lane rows; row_bcast15/31 to cross rows.
    x += __int_as_float(__builtin_amdgcn_update_dpp(0, __float_as_int(x), 0x111, 0xf, 0xf, false));
    x += __int_as_float(__builtin_amdgcn_update_dpp(0, __float_as_int(x), 0x112, 0xf, 0xf, false));
    x += __int_as_float(__builtin_amdgcn_update_dpp(0, __float_as_int(x), 0x114, 0xf, 0xf, false));
    x += __int_as_float(__builtin_amdgcn_update_dpp(0, __float_as_int(x), 0x118, 0xf, 0xf, false));
    x += __int_as_float(__builtin_amdgcn_update_dpp(0, __float_as_int(x), 0x142, 0xa, 0xf, false));
    x += __int_as_float(__builtin_amdgcn_update_dpp(0, __float_as_int(x), 0x143, 0xc, 0xf, false));
    return __int_as_float(__builtin_amdgcn_readlane(__float_as_int(x), 63));
}

// ---------------- K6: sequential coherent scan (1 wave per batch) ----------
// Reads msk_n rows from mskn_gen, overwrites each row in place with gen.
// Safe in-place: row m is last READ at iteration m-2 (prefetch), WRITTEN at m.
__global__ __launch_bounds__(64, 1) void k_scan(float* __restrict__ mskn_gen,
    const float* __restrict__ best, const float* __restrict__ maxc)
{
    int b = blockIdx.x;
    int lane = threadIdx.x;
    float4* mg4 = (float4*)(mskn_gen + (size_t)b * M_ * C_);
    const float4* bs4 = (const float4*)(best + (size_t)b * M_ * C_);
    const float* mx_p = maxc + b * M_;

    float pr[8];
#pragma unroll
    for (int j = 0; j < 8; ++j) pr[j] = 0.f;

    float4 mf[3][2], bf[3][2]; float mx[3];
#pragma unroll
    for (int s = 0; s < 2; ++s) {
        int base = s * 128 + lane * 2;
        mf[s][0] = mg4[base]; mf[s][1] = mg4[base + 1];
        bf[s][0] = bs4[base]; bf[s][1] = bs4[base + 1];
        mx[s] = mx_p[s];
    }

#pragma unroll 3
    for (int m = 0; m < M_; ++m) {
        int cur = m % 3;
        int nxt = (m + 2) % 3;
        if (m + 2 < M_) {                     // prefetch distance 2
            int base = (m + 2) * 128 + lane * 2;
            mf[nxt][0] = mg4[base]; mf[nxt][1] = mg4[base + 1];
            bf[nxt][0] = bs4[base]; bf[nxt][1] = bs4[base + 1];
            mx[nxt] = mx_p[m + 2];
        }
        float mn[8] = {mf[cur][0].x, mf[cur][0].y, mf[cur][0].z, mf[cur][0].w,
                       mf[cur][1].x, mf[cur][1].y, mf[cur][1].z, mf[cur][1].w};
        float bs[8] = {bf[cur][0].x, bf[cur][0].y, bf[cur][0].z, bf[cur][0].w,
                       bf[cur][1].x, bf[cur][1].y, bf[cur][1].z, bf[cur][1].w};
        // two-chain FMA trees to shorten the serial depth
        float s1a = 0.f, s1b = 0.f, s2a = 0.f, s2b = 0.f;
#pragma unroll
        for (int j = 0; j < 4; ++j) {
            s1a = fmaf(pr[j], pr[j], s1a);
            s1b = fmaf(pr[j + 4], pr[j + 4], s1b);
            s2a = fmaf(mn[j], pr[j], s2a);
            s2b = fmaf(mn[j + 4], pr[j + 4], s2b);
        }
        float s1 = wave_sum64(s1a + s1b);
        float s2 = wave_sum64(s2a + s2b);
        float d_ad = fmaxf(s2, 0.f) * __builtin_amdgcn_rcpf(sqrtf(s1) + EPS_);
        float inv  = __builtin_amdgcn_rcpf(d_ad + mx[cur] + EPS_);
#pragma unroll
        for (int j = 0; j < 8; ++j)
            pr[j] = (d_ad * pr[j] + mx[cur] * bs[j]) * inv;
        float4 o0 = {pr[0], pr[1], pr[2], pr[3]};
        float4 o1 = {pr[4], pr[5], pr[6], pr[7]};
        int sb = m * 128 + lane * 2;
        mg4[sb] = o0; mg4[sb + 1] = o1;       // dense coalesced gen write
    }
}

// ---------------- K7: scatter gen rows into masked columns of out ----------
// grid = 256 blocks: b(8) x hole-row(32); block = 256 threads
__global__ __launch_bounds__(256) void k_scatter(const float* __restrict__ gen,
    const int* __restrict__ m_idx, float* __restrict__ out)
{
    __shared__ float T[32][513];
    __shared__ int ps[32];
    int blk = blockIdx.x;
    int b = blk >> 5, row = blk & 31;
    int m0 = row * 32;
    int t = threadIdx.x;
    if (t < 32) ps[t] = m_idx[m0 + t];
    const float* gb = gen + ((size_t)(b << 10) + m0) * C_;
    // coalesced read gen[b][m0+i][c] -> T[i][c]
#pragma unroll 4
    for (int rep = 0; rep < 64; ++rep) {
        int idx = rep * 256 + t;
        int i = idx >> 9, c = idx & 511;
        T[i][c] = gb[(size_t)i * C_ + c];
    }
    __syncthreads();
    float* ob = out + (size_t)b * C_ * HW_;
    // write out[b][c][ps[i]] : 32 consecutive columns per c -> 128B segments
#pragma unroll 4
    for (int rep = 0; rep < 64; ++rep) {
        int idx = rep * 256 + t;
        int c = idx >> 5, i = idx & 31;
        ob[(size_t)c * HW_ + ps[i]] = T[i][c];
    }
}

// ---------------- launch ----------------------------------------------------
extern "C" void kernel_launch(void* const* d_in, const int* in_sizes, int n_in,
                              void* d_out, int out_size, void* d_ws, size_t ws_size,
                              hipStream_t stream) {
    (void)in_sizes; (void)n_in; (void)out_size; (void)ws_size;
    const float* x      = (const float*)d_in[0];
    const int*   nm_idx = (const int*)d_in[2];
    const int*   m_idx  = (const int*)d_in[3];
    float* out = (float*)d_out;
    char* ws = (char*)d_ws;

    float* inv_all = (float*)(ws + 0);          // 131072 B
    float* pmax    = (float*)(ws + 131072);     // 131072 B  [8192][2 split][2 rank]
    int*   pidx    = (int*)  (ws + 262144);     // 131072 B
    float* maxc    = (float*)(ws + 393216);     // 32768 B
    int*   bestp   = (int*)  (ws + 425984);     // 32768 B
    float* mskn    = (float*)(ws + 458752);     // 16 MB; scan overwrites in place with gen
    float* best    = (float*)(ws + 17235968);   // 16 MB  (end ~33.4 MB)

    hipLaunchKernelGGL(k_norms,   dim3(256),  dim3(128), 0, stream, x, inv_all);
    hipLaunchKernelGGL(k_cos,     dim3(512),  dim3(256), 0, stream, x, nm_idx, m_idx, inv_all, pmax, pidx);
    hipLaunchKernelGGL(k_combine, dim3(32),   dim3(256), 0, stream, x, nm_idx, m_idx, pmax, pidx, maxc, bestp);
    hipLaunchKernelGGL(k_copy,    dim3(2048), dim3(256), 0, stream, (const float4*)x, (float4*)out);
    hipLaunchKernelGGL(k_gather,  dim3(256),  dim3(256), 0, stream, x, m_idx, inv_all, bestp, mskn, best);
    hipLaunchKernelGGL(k_scan,    dim3(8),    dim3(64),  0, stream, mskn, best, maxc);
    hipLaunchKernelGGL(k_scatter, dim3(256),  dim3(256), 0, stream, mskn, m_idx, out);
}

// Round 3
// 1364.277 us; speedup vs baseline: 1.5527x; 1.5527x over previous
//
#include <hip/hip_runtime.h>
#include <hip/hip_bf16.h>

#define B_   8
#define C_   512
#define HW_  4096
#define M_   1024
#define N_   3072
#define EPS_ 1e-8f

#define KCH   16
#define NTILE 512

// ---------------- K1: per-column inverse norms (all 4096 columns) ----------
__global__ void k_norms(const float* __restrict__ x, float* __restrict__ inv_all) {
    int blk = blockIdx.x;            // 256 blocks = 8 b * 32 chunks
    int b = blk >> 5;
    int chunk = blk & 31;
    int hw = chunk * 128 + threadIdx.x;   // 128 threads
    const float* xb = x + (size_t)b * C_ * HW_;
    float acc = 0.f;
#pragma unroll 8
    for (int c = 0; c < C_; ++c) {
        float v = xb[(size_t)c * HW_ + hw];
        acc = fmaf(v, v, acc);
    }
    inv_all[b * HW_ + hw] = 1.0f / (sqrtf(acc) + EPS_);
}

// ---------------- K2: cos-sim GEMM + per-row top-2 ------------------------
// grid = 512 blocks: b(8) x mtile(32, 32 rows each) x nsplit(2, 1536 each)
// block = 256 threads = 4 tm x 64 tn ; microtile 8m x 8n ; tile 32m x 512n
__global__ __launch_bounds__(256, 2) void k_cos(
    const float* __restrict__ x, const int* __restrict__ nm_idx,
    const int* __restrict__ m_idx, const float* __restrict__ inv_all,
    float* __restrict__ pmax, int* __restrict__ pidx)
{
    __shared__ float As[KCH][32];
    __shared__ float Bs[KCH][NTILE];
    __shared__ int   nsp[NTILE];
    __shared__ float invc[NTILE];
    __shared__ int   ps[32];
    __shared__ float invm[32];

    int blk = blockIdx.x;
    int b     = blk >> 6;
    int mt    = (blk >> 1) & 31;
    int split = blk & 1;
    int m0 = mt * 32;
    int t  = threadIdx.x;
    int tn = t & 63;
    int tm = t >> 6;

    const float* xb   = x + (size_t)b * C_ * HW_;
    const float* invb = inv_all + b * HW_;

    if (t < 32) {
        int p = m_idx[m0 + t];
        ps[t] = p;
        invm[t] = invb[p];
    }

    float v1[8], v2[8]; int i1[8], i2[8];
#pragma unroll
    for (int mi = 0; mi < 8; ++mi) {
        v1[mi] = -3.402823466e38f; v2[mi] = -3.402823466e38f;
        i1[mi] = 0x7fffffff;       i2[mi] = 0x7fffffff;
    }

    int nbase = split * 1536;
    for (int nt = 0; nt < 1536; nt += NTILE) {
        __syncthreads();   // protect nsp/invc (and ps/invm on first pass)
        {
            int j = t;
            int p = nm_idx[nbase + nt + j];
            nsp[j] = p; invc[j] = invb[p];
            j = t + 256;
            p = nm_idx[nbase + nt + j];
            nsp[j] = p; invc[j] = invb[p];
        }
        __syncthreads();

        float acc[8][8];
#pragma unroll
        for (int a = 0; a < 8; ++a)
#pragma unroll
            for (int q = 0; q < 8; ++q) acc[a][q] = 0.f;

        for (int k0 = 0; k0 < C_; k0 += KCH) {
            // stage A: 16k x 32m
            {
                int idx = t;
                int kk = idx >> 5, i = idx & 31;
                As[kk][i] = xb[(size_t)(k0 + kk) * HW_ + ps[i]];
                idx = t + 256; kk = idx >> 5; i = idx & 31;
                As[kk][i] = xb[(size_t)(k0 + kk) * HW_ + ps[i]];
            }
            // stage B: 16k x 512n
#pragma unroll
            for (int rep = 0; rep < 32; ++rep) {
                int idx = rep * 256 + t;
                int kk = idx >> 9, j = idx & 511;
                Bs[kk][j] = xb[(size_t)(k0 + kk) * HW_ + nsp[j]];
            }
            __syncthreads();
#pragma unroll
            for (int kk = 0; kk < KCH; ++kk) {
                float a[8], bb[8];
                *(float4*)&a[0]  = *(const float4*)&As[kk][tm * 8];
                *(float4*)&a[4]  = *(const float4*)&As[kk][tm * 8 + 4];
                *(float4*)&bb[0] = *(const float4*)&Bs[kk][tn * 4];
                *(float4*)&bb[4] = *(const float4*)&Bs[kk][256 + tn * 4];
#pragma unroll
                for (int mi = 0; mi < 8; ++mi)
#pragma unroll
                    for (int nj = 0; nj < 8; ++nj)
                        acc[mi][nj] = fmaf(a[mi], bb[nj], acc[mi][nj]);
            }
            __syncthreads();
        }
        // epilogue: scale to cosine, insert into top-2
#pragma unroll
        for (int mi = 0; mi < 8; ++mi) {
            float im = invm[tm * 8 + mi];
#pragma unroll
            for (int nj = 0; nj < 8; ++nj) {
                int jl = (nj < 4) ? (tn * 4 + nj) : (256 + tn * 4 + nj - 4);
                float v = acc[mi][nj] * im * invc[jl];
                int n = nbase + nt + jl;
                if (v > v1[mi] || (v == v1[mi] && n < i1[mi])) {
                    v2[mi] = v1[mi]; i2[mi] = i1[mi]; v1[mi] = v; i1[mi] = n;
                } else if (v > v2[mi] || (v == v2[mi] && n < i2[mi])) {
                    v2[mi] = v; i2[mi] = n;
                }
            }
        }
    }

    // wave butterfly top-2 reduction (each wave == one tm, covers 8 m's)
#pragma unroll
    for (int mi = 0; mi < 8; ++mi) {
        float a1v = v1[mi], a2v = v2[mi]; int a1i = i1[mi], a2i = i2[mi];
        for (int off = 32; off; off >>= 1) {
            float o1v = __shfl_xor(a1v, off, 64); int o1i = __shfl_xor(a1i, off, 64);
            float o2v = __shfl_xor(a2v, off, 64); int o2i = __shfl_xor(a2i, off, 64);
            if (o1v > a1v || (o1v == a1v && o1i < a1i)) { a2v = a1v; a2i = a1i; a1v = o1v; a1i = o1i; }
            else if (o1v > a2v || (o1v == a2v && o1i < a2i)) { a2v = o1v; a2i = o1i; }
            if (o2v > a1v || (o2v == a1v && o2i < a1i)) { a2v = a1v; a2i = a1i; a1v = o2v; a1i = o2i; }
            else if (o2v > a2v || (o2v == a2v && o2i < a2i)) { a2v = o2v; a2i = o2i; }
        }
        if (tn == 0) {
            int m = m0 + tm * 8 + mi;
            int id = (b << 10) + m;
            int o = id * 4 + split * 2;     // [id][split][rank]
            pmax[o + 0] = a1v; pidx[o + 0] = a1i;
            pmax[o + 1] = a2v; pidx[o + 1] = a2i;
        }
    }
}

// ---------------- K3: combine splits + fp64 re-check near-ties -------------
__global__ void k_combine(const float* __restrict__ x,
    const int* __restrict__ nm_idx, const int* __restrict__ m_idx,
    const float* __restrict__ pmax, const int* __restrict__ pidx,
    float* __restrict__ maxc, int* __restrict__ bestp)
{
    int id = blockIdx.x * 256 + threadIdx.x;     // 8192
    int b = id >> 10, m = id & 1023;
    float v1 = -3.402823466e38f, v2 = -3.402823466e38f;
    int i1 = 0x7fffffff, i2 = 0x7fffffff;
#pragma unroll
    for (int r = 0; r < 4; ++r) {
        float v = pmax[id * 4 + r];
        int   n = pidx[id * 4 + r];
        if (v > v1 || (v == v1 && n < i1)) { v2 = v1; i2 = i1; v1 = v; i1 = n; }
        else if (v > v2 || (v == v2 && n < i2)) { v2 = v; i2 = n; }
    }
    if (v1 - v2 < 1e-5f) {
        // exact fp64 decision between the two candidates
        const float* xb = x + (size_t)b * C_ * HW_;
        int pm = m_idx[m], p1 = nm_idx[i1], p2 = nm_idx[i2];
        double smm = 0, s11 = 0, s22 = 0, sm1 = 0, sm2 = 0;
        for (int c = 0; c < C_; ++c) {
            double xm = xb[(size_t)c * HW_ + pm];
            double xa = xb[(size_t)c * HW_ + p1];
            double xc = xb[(size_t)c * HW_ + p2];
            smm += xm * xm; s11 += xa * xa; s22 += xc * xc;
            sm1 += xm * xa; sm2 += xm * xc;
        }
        double inv_m = 1.0 / (sqrt(smm) + 1e-8);
        double c1 = sm1 * inv_m / (sqrt(s11) + 1e-8);
        double c2 = sm2 * inv_m / (sqrt(s22) + 1e-8);
        if (c2 > c1 || (c2 == c1 && i2 < i1)) { v1 = v2; i1 = i2; }
    }
    maxc[id]  = v1;
    bestp[id] = nm_idx[i1];
}

// ---------------- K4: copy input -> output (context passthrough) -----------
__global__ void k_copy(const float4* __restrict__ in, float4* __restrict__ out) {
    int idx = blockIdx.x * 256 + threadIdx.x;
    int stride = gridDim.x * 256;
    for (int i = idx; i < (B_ * C_ * HW_ / 4); i += stride) out[i] = in[i];
}

// ---------------- K5: gather dense msk_n and best buffers ------------------
// grid = 256 blocks: b(8) x hole-row(32); block = 256 threads
__global__ __launch_bounds__(256) void k_gather(const float* __restrict__ x,
    const int* __restrict__ m_idx, const float* __restrict__ inv_all,
    const int* __restrict__ bestp, float* __restrict__ mskn, float* __restrict__ best)
{
    __shared__ float T[32][513];
    __shared__ int ps[32]; __shared__ float invm[32]; __shared__ int bp[32];
    int blk = blockIdx.x;
    int b = blk >> 5, row = blk & 31;
    int m0 = row * 32;
    int t = threadIdx.x;
    const float* xb = x + (size_t)b * C_ * HW_;
    if (t < 32) {
        int p = m_idx[m0 + t];
        ps[t] = p; invm[t] = inv_all[b * HW_ + p];
        bp[t] = bestp[(b << 10) + m0 + t];
    }
    __syncthreads();
    // transpose-load mask features: x[b][c][p_i] -> T[i][c]
#pragma unroll 4
    for (int rep = 0; rep < 64; ++rep) {
        int idx = rep * 256 + t;
        int c = idx >> 5, i = idx & 31;
        T[i][c] = xb[(size_t)c * HW_ + ps[i]];
    }
    __syncthreads();
#pragma unroll 4
    for (int rep = 0; rep < 64; ++rep) {
        int idx = rep * 256 + t;
        int i = idx >> 9, c = idx & 511;
        mskn[((size_t)(b << 10) + m0 + i) * C_ + c] = T[i][c] * invm[i];
    }
    // best: scattered reads, coalesced writes
    for (int mi = 0; mi < 32; ++mi) {
        int p = bp[mi];
        size_t o = ((size_t)(b << 10) + m0 + mi) * C_;
        for (int c = t; c < C_; c += 256)
            best[o + c] = xb[(size_t)c * HW_ + p];
    }
}

// ---------------- DPP wave-64 sum: result broadcast via readlane(63) -------
__device__ __forceinline__ float wave_sum64(float x) {
    // row_shr 1,2,4,8 within 16-lane rows; row_bcast15/31 to cross rows.
    x += __int_as_float(__builtin_amdgcn_update_dpp(0, __float_as_int(x), 0x111, 0xf, 0xf, false));
    x += __int_as_float(__builtin_amdgcn_update_dpp(0, __float_as_int(x), 0x112, 0xf, 0xf, false));
    x += __int_as_float(__builtin_amdgcn_update_dpp(0, __float_as_int(x), 0x114, 0xf, 0xf, false));
    x += __int_as_float(__builtin_amdgcn_update_dpp(0, __float_as_int(x), 0x118, 0xf, 0xf, false));
    x += __int_as_float(__builtin_amdgcn_update_dpp(0, __float_as_int(x), 0x142, 0xa, 0xf, false));
    x += __int_as_float(__builtin_amdgcn_update_dpp(0, __float_as_int(x), 0x143, 0xc, 0xf, false));
    return __int_as_float(__builtin_amdgcn_readlane(__float_as_int(x), 63));
}

// ---------------- K6: sequential coherent scan (1 wave per batch) ----------
// Reads from distinct __restrict__ buffers only; writes ONLY to `out`
// (never loaded here) -> stores are fire-and-forget, no alias ordering.
// 8-slot register cyclic buffer, prefetch distance 7, loop unrolled x8 so
// all buffer indices are static (no scratch spill from dynamic indexing).
__global__ __launch_bounds__(64, 1) void k_scan(const float* __restrict__ mskn,
    const float* __restrict__ best, const float* __restrict__ maxc,
    const int* __restrict__ m_idx, float* __restrict__ out)
{
    int b = blockIdx.x;
    int lane = threadIdx.x;
    const float4* mn4 = (const float4*)(mskn + (size_t)b * M_ * C_);
    const float4* bs4 = (const float4*)(best + (size_t)b * M_ * C_);
    const float* mx_p = maxc + b * M_;
    float* outb = out + (size_t)b * C_ * HW_;

    float pr[8];
#pragma unroll
    for (int j = 0; j < 8; ++j) pr[j] = 0.f;

    float4 mf[8][2], bf[8][2]; float mx[8]; int col[8];
#pragma unroll
    for (int s = 0; s < 7; ++s) {
        int base = s * 128 + lane * 2;
        mf[s][0] = mn4[base]; mf[s][1] = mn4[base + 1];
        bf[s][0] = bs4[base]; bf[s][1] = bs4[base + 1];
        mx[s] = mx_p[s]; col[s] = m_idx[s];
    }

#pragma unroll 8
    for (int m = 0; m < M_; ++m) {
        int cur = m & 7;
        if (m + 7 < M_) {                     // prefetch distance 7
            int s = (m + 7) & 7;              // == (m-1)&7 : consumed last iter
            int base = (m + 7) * 128 + lane * 2;
            mf[s][0] = mn4[base]; mf[s][1] = mn4[base + 1];
            bf[s][0] = bs4[base]; bf[s][1] = bs4[base + 1];
            mx[s] = mx_p[m + 7]; col[s] = m_idx[m + 7];
        }
        float mn[8] = {mf[cur][0].x, mf[cur][0].y, mf[cur][0].z, mf[cur][0].w,
                       mf[cur][1].x, mf[cur][1].y, mf[cur][1].z, mf[cur][1].w};
        float bs[8] = {bf[cur][0].x, bf[cur][0].y, bf[cur][0].z, bf[cur][0].w,
                       bf[cur][1].x, bf[cur][1].y, bf[cur][1].z, bf[cur][1].w};
        // two-chain FMA trees to shorten the serial depth
        float s1a = 0.f, s1b = 0.f, s2a = 0.f, s2b = 0.f;
#pragma unroll
        for (int j = 0; j < 4; ++j) {
            s1a = fmaf(pr[j], pr[j], s1a);
            s1b = fmaf(pr[j + 4], pr[j + 4], s1b);
            s2a = fmaf(mn[j], pr[j], s2a);
            s2b = fmaf(mn[j + 4], pr[j + 4], s2b);
        }
        float s1 = wave_sum64(s1a + s1b);
        float s2 = wave_sum64(s2a + s2b);
        float mxc = mx[cur];
        float d_ad = fmaxf(s2, 0.f) * __builtin_amdgcn_rcpf(sqrtf(s1) + EPS_);
        float inv  = __builtin_amdgcn_rcpf(d_ad + mxc + EPS_);
#pragma unroll
        for (int j = 0; j < 8; ++j)
            pr[j] = (d_ad * pr[j] + mxc * bs[j]) * inv;
        // scattered stores to final location; off the serial chain
        int c = col[cur];
#pragma unroll
        for (int j = 0; j < 8; ++j)
            outb[(size_t)(lane * 8 + j) * HW_ + c] = pr[j];
    }
}

// ---------------- launch ----------------------------------------------------
extern "C" void kernel_launch(void* const* d_in, const int* in_sizes, int n_in,
                              void* d_out, int out_size, void* d_ws, size_t ws_size,
                              hipStream_t stream) {
    (void)in_sizes; (void)n_in; (void)out_size; (void)ws_size;
    const float* x      = (const float*)d_in[0];
    const int*   nm_idx = (const int*)d_in[2];
    const int*   m_idx  = (const int*)d_in[3];
    float* out = (float*)d_out;
    char* ws = (char*)d_ws;

    float* inv_all = (float*)(ws + 0);          // 131072 B
    float* pmax    = (float*)(ws + 131072);     // 131072 B  [8192][2 split][2 rank]
    int*   pidx    = (int*)  (ws + 262144);     // 131072 B
    float* maxc    = (float*)(ws + 393216);     // 32768 B
    int*   bestp   = (int*)  (ws + 425984);     // 32768 B
    float* mskn    = (float*)(ws + 458752);     // 16 MB
    float* best    = (float*)(ws + 17235968);   // 16 MB  (end ~33.4 MB)

    hipLaunchKernelGGL(k_norms,   dim3(256),  dim3(128), 0, stream, x, inv_all);
    hipLaunchKernelGGL(k_cos,     dim3(512),  dim3(256), 0, stream, x, nm_idx, m_idx, inv_all, pmax, pidx);
    hipLaunchKernelGGL(k_combine, dim3(32),   dim3(256), 0, stream, x, nm_idx, m_idx, pmax, pidx, maxc, bestp);
    hipLaunchKernelGGL(k_copy,    dim3(2048), dim3(256), 0, stream, (const float4*)x, (float4*)out);
    hipLaunchKernelGGL(k_gather,  dim3(256),  dim3(256), 0, stream, x, m_idx, inv_all, bestp, mskn, best);
    hipLaunchKernelGGL(k_scan,    dim3(8),    dim3(64),  0, stream, mskn, best, maxc, m_idx, out);
}

// Round 4
// 1072.338 us; speedup vs baseline: 1.9754x; 1.2722x over previous
//
#include <hip/hip_runtime.h>
#include <hip/hip_bf16.h>

#define B_   8
#define C_   512
#define HW_  4096
#define M_   1024
#define N_   3072
#define EPS_ 1e-8f

#define KCH   16
#define NTILE 512

// ---------------- K1: per-column inverse norms (all 4096 columns) ----------
__global__ void k_norms(const float* __restrict__ x, float* __restrict__ inv_all) {
    int blk = blockIdx.x;            // 256 blocks = 8 b * 32 chunks
    int b = blk >> 5;
    int chunk = blk & 31;
    int hw = chunk * 128 + threadIdx.x;   // 128 threads
    const float* xb = x + (size_t)b * C_ * HW_;
    float acc = 0.f;
#pragma unroll 8
    for (int c = 0; c < C_; ++c) {
        float v = xb[(size_t)c * HW_ + hw];
        acc = fmaf(v, v, acc);
    }
    inv_all[b * HW_ + hw] = 1.0f / (sqrtf(acc) + EPS_);
}

// ---------------- K2: cos-sim GEMM + per-row top-2 ------------------------
// grid = 512 blocks: b(8) x mtile(32, 32 rows each) x nsplit(2, 1536 each)
// block = 256 threads = 4 tm x 64 tn ; microtile 8m x 8n ; tile 32m x 512n
__global__ __launch_bounds__(256, 2) void k_cos(
    const float* __restrict__ x, const int* __restrict__ nm_idx,
    const int* __restrict__ m_idx, const float* __restrict__ inv_all,
    float* __restrict__ pmax, int* __restrict__ pidx)
{
    __shared__ float As[KCH][32];
    __shared__ float Bs[KCH][NTILE];
    __shared__ int   nsp[NTILE];
    __shared__ float invc[NTILE];
    __shared__ int   ps[32];
    __shared__ float invm[32];

    int blk = blockIdx.x;
    int b     = blk >> 6;
    int mt    = (blk >> 1) & 31;
    int split = blk & 1;
    int m0 = mt * 32;
    int t  = threadIdx.x;
    int tn = t & 63;
    int tm = t >> 6;

    const float* xb   = x + (size_t)b * C_ * HW_;
    const float* invb = inv_all + b * HW_;

    if (t < 32) {
        int p = m_idx[m0 + t];
        ps[t] = p;
        invm[t] = invb[p];
    }

    float v1[8], v2[8]; int i1[8], i2[8];
#pragma unroll
    for (int mi = 0; mi < 8; ++mi) {
        v1[mi] = -3.402823466e38f; v2[mi] = -3.402823466e38f;
        i1[mi] = 0x7fffffff;       i2[mi] = 0x7fffffff;
    }

    int nbase = split * 1536;
    for (int nt = 0; nt < 1536; nt += NTILE) {
        __syncthreads();   // protect nsp/invc (and ps/invm on first pass)
        {
            int j = t;
            int p = nm_idx[nbase + nt + j];
            nsp[j] = p; invc[j] = invb[p];
            j = t + 256;
            p = nm_idx[nbase + nt + j];
            nsp[j] = p; invc[j] = invb[p];
        }
        __syncthreads();

        float acc[8][8];
#pragma unroll
        for (int a = 0; a < 8; ++a)
#pragma unroll
            for (int q = 0; q < 8; ++q) acc[a][q] = 0.f;

        for (int k0 = 0; k0 < C_; k0 += KCH) {
            // stage A: 16k x 32m
            {
                int idx = t;
                int kk = idx >> 5, i = idx & 31;
                As[kk][i] = xb[(size_t)(k0 + kk) * HW_ + ps[i]];
                idx = t + 256; kk = idx >> 5; i = idx & 31;
                As[kk][i] = xb[(size_t)(k0 + kk) * HW_ + ps[i]];
            }
            // stage B: 16k x 512n
#pragma unroll
            for (int rep = 0; rep < 32; ++rep) {
                int idx = rep * 256 + t;
                int kk = idx >> 9, j = idx & 511;
                Bs[kk][j] = xb[(size_t)(k0 + kk) * HW_ + nsp[j]];
            }
            __syncthreads();
#pragma unroll
            for (int kk = 0; kk < KCH; ++kk) {
                float a[8], bb[8];
                *(float4*)&a[0]  = *(const float4*)&As[kk][tm * 8];
                *(float4*)&a[4]  = *(const float4*)&As[kk][tm * 8 + 4];
                *(float4*)&bb[0] = *(const float4*)&Bs[kk][tn * 4];
                *(float4*)&bb[4] = *(const float4*)&Bs[kk][256 + tn * 4];
#pragma unroll
                for (int mi = 0; mi < 8; ++mi)
#pragma unroll
                    for (int nj = 0; nj < 8; ++nj)
                        acc[mi][nj] = fmaf(a[mi], bb[nj], acc[mi][nj]);
            }
            __syncthreads();
        }
        // epilogue: scale to cosine, insert into top-2
#pragma unroll
        for (int mi = 0; mi < 8; ++mi) {
            float im = invm[tm * 8 + mi];
#pragma unroll
            for (int nj = 0; nj < 8; ++nj) {
                int jl = (nj < 4) ? (tn * 4 + nj) : (256 + tn * 4 + nj - 4);
                float v = acc[mi][nj] * im * invc[jl];
                int n = nbase + nt + jl;
                if (v > v1[mi] || (v == v1[mi] && n < i1[mi])) {
                    v2[mi] = v1[mi]; i2[mi] = i1[mi]; v1[mi] = v; i1[mi] = n;
                } else if (v > v2[mi] || (v == v2[mi] && n < i2[mi])) {
                    v2[mi] = v; i2[mi] = n;
                }
            }
        }
    }

    // wave butterfly top-2 reduction (each wave == one tm, covers 8 m's)
#pragma unroll
    for (int mi = 0; mi < 8; ++mi) {
        float a1v = v1[mi], a2v = v2[mi]; int a1i = i1[mi], a2i = i2[mi];
        for (int off = 32; off; off >>= 1) {
            float o1v = __shfl_xor(a1v, off, 64); int o1i = __shfl_xor(a1i, off, 64);
            float o2v = __shfl_xor(a2v, off, 64); int o2i = __shfl_xor(a2i, off, 64);
            if (o1v > a1v || (o1v == a1v && o1i < a1i)) { a2v = a1v; a2i = a1i; a1v = o1v; a1i = o1i; }
            else if (o1v > a2v || (o1v == a2v && o1i < a2i)) { a2v = o1v; a2i = o1i; }
            if (o2v > a1v || (o2v == a1v && o2i < a1i)) { a2v = a1v; a2i = a1i; a1v = o2v; a1i = o2i; }
            else if (o2v > a2v || (o2v == a2v && o2i < a2i)) { a2v = o2v; a2i = o2i; }
        }
        if (tn == 0) {
            int m = m0 + tm * 8 + mi;
            int id = (b << 10) + m;
            int o = id * 4 + split * 2;     // [id][split][rank]
            pmax[o + 0] = a1v; pidx[o + 0] = a1i;
            pmax[o + 1] = a2v; pidx[o + 1] = a2i;
        }
    }
}

// ---------------- K3: combine splits + fp64 re-check near-ties -------------
__global__ void k_combine(const float* __restrict__ x,
    const int* __restrict__ nm_idx, const int* __restrict__ m_idx,
    const float* __restrict__ pmax, const int* __restrict__ pidx,
    float* __restrict__ maxc, int* __restrict__ bestp)
{
    int id = blockIdx.x * 256 + threadIdx.x;     // 8192
    int b = id >> 10, m = id & 1023;
    float v1 = -3.402823466e38f, v2 = -3.402823466e38f;
    int i1 = 0x7fffffff, i2 = 0x7fffffff;
#pragma unroll
    for (int r = 0; r < 4; ++r) {
        float v = pmax[id * 4 + r];
        int   n = pidx[id * 4 + r];
        if (v > v1 || (v == v1 && n < i1)) { v2 = v1; i2 = i1; v1 = v; i1 = n; }
        else if (v > v2 || (v == v2 && n < i2)) { v2 = v; i2 = n; }
    }
    if (v1 - v2 < 1e-5f) {
        // exact fp64 decision between the two candidates
        const float* xb = x + (size_t)b * C_ * HW_;
        int pm = m_idx[m], p1 = nm_idx[i1], p2 = nm_idx[i2];
        double smm = 0, s11 = 0, s22 = 0, sm1 = 0, sm2 = 0;
        for (int c = 0; c < C_; ++c) {
            double xm = xb[(size_t)c * HW_ + pm];
            double xa = xb[(size_t)c * HW_ + p1];
            double xc = xb[(size_t)c * HW_ + p2];
            smm += xm * xm; s11 += xa * xa; s22 += xc * xc;
            sm1 += xm * xa; sm2 += xm * xc;
        }
        double inv_m = 1.0 / (sqrt(smm) + 1e-8);
        double c1 = sm1 * inv_m / (sqrt(s11) + 1e-8);
        double c2 = sm2 * inv_m / (sqrt(s22) + 1e-8);
        if (c2 > c1 || (c2 == c1 && i2 < i1)) { v1 = v2; i1 = i2; }
    }
    maxc[id]  = v1;
    bestp[id] = nm_idx[i1];
}

// ---------------- K4: copy input -> output (context passthrough) -----------
__global__ void k_copy(const float4* __restrict__ in, float4* __restrict__ out) {
    int idx = blockIdx.x * 256 + threadIdx.x;
    int stride = gridDim.x * 256;
    for (int i = idx; i < (B_ * C_ * HW_ / 4); i += stride) out[i] = in[i];
}

// ---------------- K5: gather dense msk_n and best buffers ------------------
// grid = 256 blocks: b(8) x hole-row(32); block = 256 threads
__global__ __launch_bounds__(256) void k_gather(const float* __restrict__ x,
    const int* __restrict__ m_idx, const float* __restrict__ inv_all,
    const int* __restrict__ bestp, float* __restrict__ mskn, float* __restrict__ best)
{
    __shared__ float T[32][513];
    __shared__ int ps[32]; __shared__ float invm[32]; __shared__ int bp[32];
    int blk = blockIdx.x;
    int b = blk >> 5, row = blk & 31;
    int m0 = row * 32;
    int t = threadIdx.x;
    const float* xb = x + (size_t)b * C_ * HW_;
    if (t < 32) {
        int p = m_idx[m0 + t];
        ps[t] = p; invm[t] = inv_all[b * HW_ + p];
        bp[t] = bestp[(b << 10) + m0 + t];
    }
    __syncthreads();
    // transpose-load mask features: x[b][c][p_i] -> T[i][c]
#pragma unroll 4
    for (int rep = 0; rep < 64; ++rep) {
        int idx = rep * 256 + t;
        int c = idx >> 5, i = idx & 31;
        T[i][c] = xb[(size_t)c * HW_ + ps[i]];
    }
    __syncthreads();
#pragma unroll 4
    for (int rep = 0; rep < 64; ++rep) {
        int idx = rep * 256 + t;
        int i = idx >> 9, c = idx & 511;
        mskn[((size_t)(b << 10) + m0 + i) * C_ + c] = T[i][c] * invm[i];
    }
    // best: scattered reads, coalesced writes
    for (int mi = 0; mi < 32; ++mi) {
        int p = bp[mi];
        size_t o = ((size_t)(b << 10) + m0 + mi) * C_;
        for (int c = t; c < C_; c += 256)
            best[o + c] = xb[(size_t)c * HW_ + p];
    }
}

// ---------------- DPP wave-64 sum: result broadcast via readlane(63) -------
__device__ __forceinline__ float wave_sum64(float x) {
    // row_shr 1,2,4,8 within 16-lane rows; row_bcast15/31 to cross rows.
    x += __int_as_float(__builtin_amdgcn_update_dpp(0, __float_as_int(x), 0x111, 0xf, 0xf, false));
    x += __int_as_float(__builtin_amdgcn_update_dpp(0, __float_as_int(x), 0x112, 0xf, 0xf, false));
    x += __int_as_float(__builtin_amdgcn_update_dpp(0, __float_as_int(x), 0x114, 0xf, 0xf, false));
    x += __int_as_float(__builtin_amdgcn_update_dpp(0, __float_as_int(x), 0x118, 0xf, 0xf, false));
    x += __int_as_float(__builtin_amdgcn_update_dpp(0, __float_as_int(x), 0x142, 0xa, 0xf, false));
    x += __int_as_float(__builtin_amdgcn_update_dpp(0, __float_as_int(x), 0x143, 0xc, 0xf, false));
    return __int_as_float(__builtin_amdgcn_readlane(__float_as_int(x), 63));
}

// ---------------- K6: sequential coherent scan (1 wave per batch) ----------
// - 8-slot register ring, prefetch distance 7, pinned with sched_barrier(0)
//   each iteration so the compiler cannot sink the loads (R2: VGPR=80 proved
//   the pipeline was collapsed; expect >=200 VGPR now).
// - gen staged 16 steps in LDS (m-major, double-buffered), flushed transposed:
//   4 lanes cooperate per output row so each store covers 16 full 64B lines
//   (32 line-txns/iter amortized vs 512 scattered 4B stores in R2).
// - Flush of group g-1 is interleaved into group g (2 row-blocks per step),
//   ds_reads issued at iteration top, consuming stores at iteration bottom.
__global__ __launch_bounds__(64, 1) void k_scan(const float* __restrict__ mskn,
    const float* __restrict__ best, const float* __restrict__ maxc,
    const int* __restrict__ m_idx, float* __restrict__ out)
{
    __shared__ float G[2][16 * 512];     // 64 KB double-buffered staging
    int b = blockIdx.x;
    int lane = threadIdx.x;
    const float4* mn4 = (const float4*)(mskn + (size_t)b * M_ * C_);
    const float4* bs4 = (const float4*)(best + (size_t)b * M_ * C_);
    const float* mx_p = maxc + b * M_;
    float* outb = out + (size_t)b * C_ * HW_;

    float pr[8];
#pragma unroll
    for (int j = 0; j < 8; ++j) pr[j] = 0.f;

    float4 mf[8][2], bf[8][2]; float mx[8];
#pragma unroll
    for (int s = 0; s < 7; ++s) {
        int base = s * 128 + lane * 2;
        mf[s][0] = mn4[base]; mf[s][1] = mn4[base + 1];
        bf[s][0] = bs4[base]; bf[s][1] = bs4[base + 1];
        mx[s] = mx_p[s];
    }

    int frow = lane >> 2;        // flush: row within 16-row block
    int fchk = lane & 3;         // flush: 16B chunk within row

    int colg_prev = 0;
    for (int mb = 0; mb < 64; ++mb) {
        int p = mb & 1;
        const float* Gf = &G[p ^ 1][0];          // previous group's staging
        int colg = m_idx[mb * 16];               // uniform; group is 16 contiguous cols
#pragma unroll
        for (int mi = 0; mi < 16; ++mi) {
            int m = mb * 16 + mi;
            int cur = mi & 7;
            int nxt = (mi + 7) & 7;
            // ---- issue loads first ----
            if (m + 7 < M_) {
                int base = (m + 7) * 128 + lane * 2;
                mf[nxt][0] = mn4[base]; mf[nxt][1] = mn4[base + 1];
                bf[nxt][0] = bs4[base]; bf[nxt][1] = bs4[base + 1];
                mx[nxt] = mx_p[m + 7];
            }
            float4 f0, f1;                        // flush chunks (group mb-1)
            if (mb > 0) {
                int c0 = (mi * 2) * 16 + frow;
                int c1 = (mi * 2 + 1) * 16 + frow;
                f0.x = Gf[(fchk * 4 + 0) * 512 + c0];
                f0.y = Gf[(fchk * 4 + 1) * 512 + c0];
                f0.z = Gf[(fchk * 4 + 2) * 512 + c0];
                f0.w = Gf[(fchk * 4 + 3) * 512 + c0];
                f1.x = Gf[(fchk * 4 + 0) * 512 + c1];
                f1.y = Gf[(fchk * 4 + 1) * 512 + c1];
                f1.z = Gf[(fchk * 4 + 2) * 512 + c1];
                f1.w = Gf[(fchk * 4 + 3) * 512 + c1];
            }
            __builtin_amdgcn_sched_barrier(0);   // pin: loads may not sink
            // ---- serial compute chain ----
            float mn[8] = {mf[cur][0].x, mf[cur][0].y, mf[cur][0].z, mf[cur][0].w,
                           mf[cur][1].x, mf[cur][1].y, mf[cur][1].z, mf[cur][1].w};
            float bs[8] = {bf[cur][0].x, bf[cur][0].y, bf[cur][0].z, bf[cur][0].w,
                           bf[cur][1].x, bf[cur][1].y, bf[cur][1].z, bf[cur][1].w};
            float s1a = 0.f, s1b = 0.f, s2a = 0.f, s2b = 0.f;
#pragma unroll
            for (int j = 0; j < 4; ++j) {
                s1a = fmaf(pr[j], pr[j], s1a);
                s1b = fmaf(pr[j + 4], pr[j + 4], s1b);
                s2a = fmaf(mn[j], pr[j], s2a);
                s2b = fmaf(mn[j + 4], pr[j + 4], s2b);
            }
            float s1 = wave_sum64(s1a + s1b);
            float s2 = wave_sum64(s2a + s2b);
            float mxc = mx[cur];
            float d_ad = fmaxf(s2, 0.f) * __builtin_amdgcn_rcpf(sqrtf(s1) + EPS_);
            float inv  = __builtin_amdgcn_rcpf(d_ad + mxc + EPS_);
#pragma unroll
            for (int j = 0; j < 8; ++j)
                pr[j] = (d_ad * pr[j] + mxc * bs[j]) * inv;
            // ---- stage gen to LDS (conflict-free b128) ----
            float4 o0 = {pr[0], pr[1], pr[2], pr[3]};
            float4 o1 = {pr[4], pr[5], pr[6], pr[7]};
            *(float4*)&G[p][mi * 512 + lane * 8]     = o0;
            *(float4*)&G[p][mi * 512 + lane * 8 + 4] = o1;
            // ---- flush stores (fire-and-forget, full 64B lines) ----
            if (mb > 0) {
                int c0 = (mi * 2) * 16 + frow;
                int c1 = (mi * 2 + 1) * 16 + frow;
                *(float4*)&outb[(size_t)c0 * HW_ + colg_prev + fchk * 4] = f0;
                *(float4*)&outb[(size_t)c1 * HW_ + colg_prev + fchk * 4] = f1;
            }
        }
        colg_prev = colg;
    }
    // final flush: group 63 lives in G[1]
    const float* Gf = &G[1][0];
#pragma unroll 4
    for (int r = 0; r < 32; ++r) {
        int c = r * 16 + frow;
        float4 v;
        v.x = Gf[(fchk * 4 + 0) * 512 + c];
        v.y = Gf[(fchk * 4 + 1) * 512 + c];
        v.z = Gf[(fchk * 4 + 2) * 512 + c];
        v.w = Gf[(fchk * 4 + 3) * 512 + c];
        *(float4*)&outb[(size_t)c * HW_ + colg_prev + fchk * 4] = v;
    }
}

// ---------------- launch ----------------------------------------------------
extern "C" void kernel_launch(void* const* d_in, const int* in_sizes, int n_in,
                              void* d_out, int out_size, void* d_ws, size_t ws_size,
                              hipStream_t stream) {
    (void)in_sizes; (void)n_in; (void)out_size; (void)ws_size;
    const float* x      = (const float*)d_in[0];
    const int*   nm_idx = (const int*)d_in[2];
    const int*   m_idx  = (const int*)d_in[3];
    float* out = (float*)d_out;
    char* ws = (char*)d_ws;

    float* inv_all = (float*)(ws + 0);          // 131072 B
    float* pmax    = (float*)(ws + 131072);     // 131072 B  [8192][2 split][2 rank]
    int*   pidx    = (int*)  (ws + 262144);     // 131072 B
    float* maxc    = (float*)(ws + 393216);     // 32768 B
    int*   bestp   = (int*)  (ws + 425984);     // 32768 B
    float* mskn    = (float*)(ws + 458752);     // 16 MB
    float* best    = (float*)(ws + 17235968);   // 16 MB  (end ~33.4 MB)

    hipLaunchKernelGGL(k_norms,   dim3(256),  dim3(128), 0, stream, x, inv_all);
    hipLaunchKernelGGL(k_cos,     dim3(512),  dim3(256), 0, stream, x, nm_idx, m_idx, inv_all, pmax, pidx);
    hipLaunchKernelGGL(k_combine, dim3(32),   dim3(256), 0, stream, x, nm_idx, m_idx, pmax, pidx, maxc, bestp);
    hipLaunchKernelGGL(k_copy,    dim3(2048), dim3(256), 0, stream, (const float4*)x, (float4*)out);
    hipLaunchKernelGGL(k_gather,  dim3(256),  dim3(256), 0, stream, x, m_idx, inv_all, bestp, mskn, best);
    hipLaunchKernelGGL(k_scan,    dim3(8),    dim3(64),  0, stream, mskn, best, maxc, m_idx, out);
}

// Round 5
// 852.719 us; speedup vs baseline: 2.4841x; 1.2576x over previous
//
#include <hip/hip_runtime.h>
#include <hip/hip_bf16.h>

#define B_   8
#define C_   512
#define HW_  4096
#define M_   1024
#define N_   3072
#define EPS_ 1e-8f

typedef __attribute__((ext_vector_type(4))) float f32x4;
typedef __attribute__((ext_vector_type(8))) short short8;

// ---------------- K1: per-column inverse norms (all 4096 columns) ----------
__global__ void k_norms(const float* __restrict__ x, float* __restrict__ inv_all) {
    int blk = blockIdx.x;            // 256 blocks = 8 b * 32 chunks
    int b = blk >> 5;
    int chunk = blk & 31;
    int hw = chunk * 128 + threadIdx.x;   // 128 threads
    const float* xb = x + (size_t)b * C_ * HW_;
    float acc = 0.f;
#pragma unroll 8
    for (int c = 0; c < C_; ++c) {
        float v = xb[(size_t)c * HW_ + hw];
        acc = fmaf(v, v, acc);
    }
    inv_all[b * HW_ + hw] = 1.0f / (sqrtf(acc) + EPS_);
}

// ---------------- K2: pack x columns into bf16 hi/lo (uint32) rows ---------
// Layout: Apk[b][m][k] / Bpk[b][n][k], element = (lo16<<16)|hi16.
// Also emits dense inverse-norm arrays invM[b][1024], invC[b][3072].
// grid = 1024 blocks: first 256 = A (8b x 32 grp), next 768 = B (8b x 96 grp)
__global__ __launch_bounds__(256) void k_pack(const float* __restrict__ x,
    const int* __restrict__ nm_idx, const int* __restrict__ m_idx,
    const float* __restrict__ inv_all,
    unsigned int* __restrict__ Apk, unsigned int* __restrict__ Bpk,
    float* __restrict__ invM, float* __restrict__ invC)
{
    __shared__ float T[32][513];
    __shared__ int ps[32];
    int blk = blockIdx.x;
    int t = threadIdx.x;
    int isA = blk < 256;
    int b, grp;
    const int* idxarr;
    if (isA) { b = blk >> 5; grp = blk & 31; idxarr = m_idx; }
    else     { int r = blk - 256; b = r / 96; grp = r % 96; idxarr = nm_idx; }
    const float* xb = x + (size_t)b * C_ * HW_;
    if (t < 32) {
        int p = idxarr[grp * 32 + t];
        ps[t] = p;
        float iv = inv_all[b * HW_ + p];
        if (isA) invM[b * 1024 + grp * 32 + t] = iv;
        else     invC[b * 3072 + grp * 32 + t] = iv;
    }
    __syncthreads();
#pragma unroll 4
    for (int rep = 0; rep < 64; ++rep) {
        int idx = rep * 256 + t;
        int c = idx >> 5, i = idx & 31;
        T[i][c] = xb[(size_t)c * HW_ + ps[i]];
    }
    __syncthreads();
    unsigned int* dst = isA ? (Apk + ((size_t)b * 1024 + grp * 32) * 512)
                            : (Bpk + ((size_t)b * 3072 + grp * 32) * 512);
#pragma unroll 4
    for (int rep = 0; rep < 64; ++rep) {
        int idx = rep * 256 + t;
        int i = idx >> 9, c = idx & 511;
        float v = T[i][c];
        __hip_bfloat16 h = __float2bfloat16(v);
        float hf = __bfloat162float(h);
        __hip_bfloat16 l = __float2bfloat16(v - hf);
        unsigned int hi = __bfloat16_as_ushort(h);
        unsigned int lo = __bfloat16_as_ushort(l);
        dst[(size_t)i * 512 + c] = (lo << 16) | hi;
    }
}

// ---------------- K3: MFMA cos-sim GEMM (bf16-split) + per-row top-2 -------
// grid = 1536 blocks: b(8) x mt(8, 128 rows) x nt(24, 128 cols)
// block = 256 thr = 4 waves; wave w: wm=(w&1)*64, wn=(w>>1)*64; 4x4 16x16 tiles
__global__ __launch_bounds__(256, 2) void k_cosm(
    const unsigned int* __restrict__ Apk, const unsigned int* __restrict__ Bpk,
    const float* __restrict__ invM, const float* __restrict__ invC,
    float* __restrict__ pmax, int* __restrict__ pidx)
{
    __shared__ unsigned int As[128 * 36];   // [m][k] stride 36 (16B-aligned, balanced banks)
    __shared__ unsigned int Bs[128 * 36];
    __shared__ float sInvM[128];
    __shared__ float sInvC[128];

    int blk = blockIdx.x;
    int b  = blk / 192;
    int r  = blk % 192;
    int mt = r / 24;
    int nt = r % 24;
    int m0 = mt * 128, n0 = nt * 128;
    int t = threadIdx.x;
    int w = t >> 6, lane = t & 63;
    int wm = (w & 1) * 64, wn = (w >> 1) * 64;
    int quad = lane >> 4, nl = lane & 15;

    if (t < 128) sInvM[t] = invM[b * 1024 + m0 + t];
    else         sInvC[t - 128] = invC[b * 3072 + n0 + (t - 128)];

    const unsigned int* gA = Apk + ((size_t)b * 1024 + m0) * 512;
    const unsigned int* gB = Bpk + ((size_t)b * 3072 + n0) * 512;

    f32x4 acc[4][4];
#pragma unroll
    for (int i = 0; i < 4; ++i)
#pragma unroll
        for (int j = 0; j < 4; ++j) acc[i][j] = (f32x4){0.f, 0.f, 0.f, 0.f};

    for (int kt = 0; kt < 16; ++kt) {
        int k0 = kt * 32;
        __syncthreads();
#pragma unroll
        for (int rep = 0; rep < 4; ++rep) {
            int idx = rep * 1024 + t * 4;
            int row = idx >> 5, col = idx & 31;
            uint4 va = *(const uint4*)(gA + (size_t)row * 512 + k0 + col);
            uint4 vb = *(const uint4*)(gB + (size_t)row * 512 + k0 + col);
            *(uint4*)&As[row * 36 + col] = va;
            *(uint4*)&Bs[row * 36 + col] = vb;
        }
        __syncthreads();

        short8 ah[4], al[4], bh[4], bl[4];
#pragma unroll
        for (int mt2 = 0; mt2 < 4; ++mt2) {
            int m = wm + mt2 * 16 + nl;
            uint4 q0 = *(const uint4*)&As[m * 36 + quad * 8];
            uint4 q1 = *(const uint4*)&As[m * 36 + quad * 8 + 4];
            uint4 H, L;
            H.x = __builtin_amdgcn_perm(q0.y, q0.x, 0x05040100u);
            H.y = __builtin_amdgcn_perm(q0.w, q0.z, 0x05040100u);
            H.z = __builtin_amdgcn_perm(q1.y, q1.x, 0x05040100u);
            H.w = __builtin_amdgcn_perm(q1.w, q1.z, 0x05040100u);
            L.x = __builtin_amdgcn_perm(q0.y, q0.x, 0x07060302u);
            L.y = __builtin_amdgcn_perm(q0.w, q0.z, 0x07060302u);
            L.z = __builtin_amdgcn_perm(q1.y, q1.x, 0x07060302u);
            L.w = __builtin_amdgcn_perm(q1.w, q1.z, 0x07060302u);
            ah[mt2] = *(short8*)&H; al[mt2] = *(short8*)&L;
        }
#pragma unroll
        for (int nt2 = 0; nt2 < 4; ++nt2) {
            int n = wn + nt2 * 16 + nl;
            uint4 q0 = *(const uint4*)&Bs[n * 36 + quad * 8];
            uint4 q1 = *(const uint4*)&Bs[n * 36 + quad * 8 + 4];
            uint4 H, L;
            H.x = __builtin_amdgcn_perm(q0.y, q0.x, 0x05040100u);
            H.y = __builtin_amdgcn_perm(q0.w, q0.z, 0x05040100u);
            H.z = __builtin_amdgcn_perm(q1.y, q1.x, 0x05040100u);
            H.w = __builtin_amdgcn_perm(q1.w, q1.z, 0x05040100u);
            L.x = __builtin_amdgcn_perm(q0.y, q0.x, 0x07060302u);
            L.y = __builtin_amdgcn_perm(q0.w, q0.z, 0x07060302u);
            L.z = __builtin_amdgcn_perm(q1.y, q1.x, 0x07060302u);
            L.w = __builtin_amdgcn_perm(q1.w, q1.z, 0x07060302u);
            bh[nt2] = *(short8*)&H; bl[nt2] = *(short8*)&L;
        }
#pragma unroll
        for (int mt2 = 0; mt2 < 4; ++mt2)
#pragma unroll
            for (int nt2 = 0; nt2 < 4; ++nt2) {
                acc[mt2][nt2] = __builtin_amdgcn_mfma_f32_16x16x32_bf16(
                    ah[mt2], bh[nt2], acc[mt2][nt2], 0, 0, 0);
                acc[mt2][nt2] = __builtin_amdgcn_mfma_f32_16x16x32_bf16(
                    ah[mt2], bl[nt2], acc[mt2][nt2], 0, 0, 0);
                acc[mt2][nt2] = __builtin_amdgcn_mfma_f32_16x16x32_bf16(
                    al[mt2], bh[nt2], acc[mt2][nt2], 0, 0, 0);
            }
    }

    // epilogue: scale to cosine; per-lane top-2 across nt2; butterfly over 16 lanes
#pragma unroll
    for (int mt2 = 0; mt2 < 4; ++mt2)
#pragma unroll
        for (int reg = 0; reg < 4; ++reg) {
            int ml = wm + mt2 * 16 + quad * 4 + reg;
            float im = sInvM[ml];
            float v1 = -3.402823466e38f, v2 = -3.402823466e38f;
            int i1 = 0x7fffffff, i2 = 0x7fffffff;
#pragma unroll
            for (int nt2 = 0; nt2 < 4; ++nt2) {
                int nlc = wn + nt2 * 16 + nl;
                float v = acc[mt2][nt2][reg] * im * sInvC[nlc];
                int n = n0 + nlc;
                if (v > v1 || (v == v1 && n < i1)) { v2 = v1; i2 = i1; v1 = v; i1 = n; }
                else if (v > v2 || (v == v2 && n < i2)) { v2 = v; i2 = n; }
            }
#pragma unroll
            for (int off = 1; off < 16; off <<= 1) {
                float o1v = __shfl_xor(v1, off, 64); int o1i = __shfl_xor(i1, off, 64);
                float o2v = __shfl_xor(v2, off, 64); int o2i = __shfl_xor(i2, off, 64);
                if (o1v > v1 || (o1v == v1 && o1i < i1)) { v2 = v1; i2 = i1; v1 = o1v; i1 = o1i; }
                else if (o1v > v2 || (o1v == v2 && o1i < i2)) { v2 = o1v; i2 = o1i; }
                if (o2v > v1 || (o2v == v1 && o2i < i1)) { v2 = v1; i2 = i1; v1 = o2v; i1 = o2i; }
                else if (o2v > v2 || (o2v == v2 && o2i < i2)) { v2 = o2v; i2 = o2i; }
            }
            if (nl == 0) {
                int m_glob = (b << 10) + m0 + ml;
                int slot = nt * 2 + (w >> 1);
                int o = (m_glob * 48 + slot) * 2;
                pmax[o + 0] = v1; pidx[o + 0] = i1;
                pmax[o + 1] = v2; pidx[o + 1] = i2;
            }
        }
}

// ---------------- K4: combine partials + fp64 re-check near-ties -----------
__global__ void k_combine(const float* __restrict__ x,
    const int* __restrict__ nm_idx, const int* __restrict__ m_idx,
    const float* __restrict__ pmax, const int* __restrict__ pidx,
    float* __restrict__ maxc, int* __restrict__ bestp)
{
    int id = blockIdx.x * 256 + threadIdx.x;     // 8192
    int b = id >> 10, m = id & 1023;
    float v1 = -3.402823466e38f, v2 = -3.402823466e38f;
    int i1 = 0x7fffffff, i2 = 0x7fffffff;
#pragma unroll 8
    for (int r = 0; r < 96; ++r) {
        float v = pmax[(size_t)id * 96 + r];
        int   n = pidx[(size_t)id * 96 + r];
        if (v > v1 || (v == v1 && n < i1)) { v2 = v1; i2 = i1; v1 = v; i1 = n; }
        else if (v > v2 || (v == v2 && n < i2)) { v2 = v; i2 = n; }
    }
    if (v1 - v2 < 1e-4f) {
        // exact fp64 decision between the two candidates
        const float* xb = x + (size_t)b * C_ * HW_;
        int pm = m_idx[m], p1 = nm_idx[i1], p2 = nm_idx[i2];
        double smm = 0, s11 = 0, s22 = 0, sm1 = 0, sm2 = 0;
        for (int c = 0; c < C_; ++c) {
            double xm = xb[(size_t)c * HW_ + pm];
            double xa = xb[(size_t)c * HW_ + p1];
            double xc = xb[(size_t)c * HW_ + p2];
            smm += xm * xm; s11 += xa * xa; s22 += xc * xc;
            sm1 += xm * xa; sm2 += xm * xc;
        }
        double inv_m = 1.0 / (sqrt(smm) + 1e-8);
        double c1 = sm1 * inv_m / (sqrt(s11) + 1e-8);
        double c2 = sm2 * inv_m / (sqrt(s22) + 1e-8);
        if (c2 > c1 || (c2 == c1 && i2 < i1)) { v1 = v2; i1 = i2; }
    }
    maxc[id]  = v1;
    bestp[id] = nm_idx[i1];
}

// ---------------- K5: copy input -> output (context passthrough) -----------
__global__ void k_copy(const float4* __restrict__ in, float4* __restrict__ out) {
    int idx = blockIdx.x * 256 + threadIdx.x;
    int stride = gridDim.x * 256;
    for (int i = idx; i < (B_ * C_ * HW_ / 4); i += stride) out[i] = in[i];
}

// ---------------- K6: gather dense msk_n and best buffers ------------------
// grid = 256 blocks: b(8) x hole-row(32); block = 256 threads
__global__ __launch_bounds__(256) void k_gather(const float* __restrict__ x,
    const int* __restrict__ m_idx, const float* __restrict__ inv_all,
    const int* __restrict__ bestp, float* __restrict__ mskn, float* __restrict__ best)
{
    __shared__ float T[32][513];
    __shared__ int ps[32]; __shared__ float invm[32]; __shared__ int bp[32];
    int blk = blockIdx.x;
    int b = blk >> 5, row = blk & 31;
    int m0 = row * 32;
    int t = threadIdx.x;
    const float* xb = x + (size_t)b * C_ * HW_;
    if (t < 32) {
        int p = m_idx[m0 + t];
        ps[t] = p; invm[t] = inv_all[b * HW_ + p];
        bp[t] = bestp[(b << 10) + m0 + t];
    }
    __syncthreads();
#pragma unroll 4
    for (int rep = 0; rep < 64; ++rep) {
        int idx = rep * 256 + t;
        int c = idx >> 5, i = idx & 31;
        T[i][c] = xb[(size_t)c * HW_ + ps[i]];
    }
    __syncthreads();
#pragma unroll 4
    for (int rep = 0; rep < 64; ++rep) {
        int idx = rep * 256 + t;
        int i = idx >> 9, c = idx & 511;
        mskn[((size_t)(b << 10) + m0 + i) * C_ + c] = T[i][c] * invm[i];
    }
    for (int mi = 0; mi < 32; ++mi) {
        int p = bp[mi];
        size_t o = ((size_t)(b << 10) + m0 + mi) * C_;
        for (int c = t; c < C_; c += 256)
            best[o + c] = xb[(size_t)c * HW_ + p];
    }
}

// ---------------- DPP wave-64 sum: result broadcast via readlane(63) -------
__device__ __forceinline__ float wave_sum64(float x) {
    x += __int_as_float(__builtin_amdgcn_update_dpp(0, __float_as_int(x), 0x111, 0xf, 0xf, false));
    x += __int_as_float(__builtin_amdgcn_update_dpp(0, __float_as_int(x), 0x112, 0xf, 0xf, false));
    x += __int_as_float(__builtin_amdgcn_update_dpp(0, __float_as_int(x), 0x114, 0xf, 0xf, false));
    x += __int_as_float(__builtin_amdgcn_update_dpp(0, __float_as_int(x), 0x118, 0xf, 0xf, false));
    x += __int_as_float(__builtin_amdgcn_update_dpp(0, __float_as_int(x), 0x142, 0xa, 0xf, false));
    x += __int_as_float(__builtin_amdgcn_update_dpp(0, __float_as_int(x), 0x143, 0xc, 0xf, false));
    return __int_as_float(__builtin_amdgcn_readlane(__float_as_int(x), 63));
}

// ---------------- K7: sequential coherent scan (1 wave per batch) ----------
__global__ __launch_bounds__(64, 1) void k_scan(const float* __restrict__ mskn,
    const float* __restrict__ best, const float* __restrict__ maxc,
    const int* __restrict__ m_idx, float* __restrict__ out)
{
    __shared__ float G[2][16 * 512];     // 64 KB double-buffered staging
    int b = blockIdx.x;
    int lane = threadIdx.x;
    const float4* mn4 = (const float4*)(mskn + (size_t)b * M_ * C_);
    const float4* bs4 = (const float4*)(best + (size_t)b * M_ * C_);
    const float* mx_p = maxc + b * M_;
    float* outb = out + (size_t)b * C_ * HW_;

    float pr[8];
#pragma unroll
    for (int j = 0; j < 8; ++j) pr[j] = 0.f;

    float4 mf[8][2], bf[8][2]; float mx[8];
#pragma unroll
    for (int s = 0; s < 7; ++s) {
        int base = s * 128 + lane * 2;
        mf[s][0] = mn4[base]; mf[s][1] = mn4[base + 1];
        bf[s][0] = bs4[base]; bf[s][1] = bs4[base + 1];
        mx[s] = mx_p[s];
    }

    int frow = lane >> 2;
    int fchk = lane & 3;

    int colg_prev = 0;
    for (int mb = 0; mb < 64; ++mb) {
        int p = mb & 1;
        const float* Gf = &G[p ^ 1][0];
        int colg = m_idx[mb * 16];
#pragma unroll
        for (int mi = 0; mi < 16; ++mi) {
            int m = mb * 16 + mi;
            int cur = mi & 7;
            int nxt = (mi + 7) & 7;
            if (m + 7 < M_) {
                int base = (m + 7) * 128 + lane * 2;
                mf[nxt][0] = mn4[base]; mf[nxt][1] = mn4[base + 1];
                bf[nxt][0] = bs4[base]; bf[nxt][1] = bs4[base + 1];
                mx[nxt] = mx_p[m + 7];
            }
            float4 f0, f1;
            if (mb > 0) {
                int c0 = (mi * 2) * 16 + frow;
                int c1 = (mi * 2 + 1) * 16 + frow;
                f0.x = Gf[(fchk * 4 + 0) * 512 + c0];
                f0.y = Gf[(fchk * 4 + 1) * 512 + c0];
                f0.z = Gf[(fchk * 4 + 2) * 512 + c0];
                f0.w = Gf[(fchk * 4 + 3) * 512 + c0];
                f1.x = Gf[(fchk * 4 + 0) * 512 + c1];
                f1.y = Gf[(fchk * 4 + 1) * 512 + c1];
                f1.z = Gf[(fchk * 4 + 2) * 512 + c1];
                f1.w = Gf[(fchk * 4 + 3) * 512 + c1];
            }
            __builtin_amdgcn_sched_barrier(0);
            float mn[8] = {mf[cur][0].x, mf[cur][0].y, mf[cur][0].z, mf[cur][0].w,
                           mf[cur][1].x, mf[cur][1].y, mf[cur][1].z, mf[cur][1].w};
            float bs[8] = {bf[cur][0].x, bf[cur][0].y, bf[cur][0].z, bf[cur][0].w,
                           bf[cur][1].x, bf[cur][1].y, bf[cur][1].z, bf[cur][1].w};
            float s1a = 0.f, s1b = 0.f, s2a = 0.f, s2b = 0.f;
#pragma unroll
            for (int j = 0; j < 4; ++j) {
                s1a = fmaf(pr[j], pr[j], s1a);
                s1b = fmaf(pr[j + 4], pr[j + 4], s1b);
                s2a = fmaf(mn[j], pr[j], s2a);
                s2b = fmaf(mn[j + 4], pr[j + 4], s2b);
            }
            float s1 = wave_sum64(s1a + s1b);
            float s2 = wave_sum64(s2a + s2b);
            float mxc = mx[cur];
            float d_ad = fmaxf(s2, 0.f) * __builtin_amdgcn_rcpf(sqrtf(s1) + EPS_);
            float inv  = __builtin_amdgcn_rcpf(d_ad + mxc + EPS_);
#pragma unroll
            for (int j = 0; j < 8; ++j)
                pr[j] = (d_ad * pr[j] + mxc * bs[j]) * inv;
            float4 o0 = {pr[0], pr[1], pr[2], pr[3]};
            float4 o1 = {pr[4], pr[5], pr[6], pr[7]};
            *(float4*)&G[p][mi * 512 + lane * 8]     = o0;
            *(float4*)&G[p][mi * 512 + lane * 8 + 4] = o1;
            if (mb > 0) {
                int c0 = (mi * 2) * 16 + frow;
                int c1 = (mi * 2 + 1) * 16 + frow;
                *(float4*)&outb[(size_t)c0 * HW_ + colg_prev + fchk * 4] = f0;
                *(float4*)&outb[(size_t)c1 * HW_ + colg_prev + fchk * 4] = f1;
            }
        }
        colg_prev = colg;
    }
    const float* Gf = &G[1][0];
#pragma unroll 4
    for (int r = 0; r < 32; ++r) {
        int c = r * 16 + frow;
        float4 v;
        v.x = Gf[(fchk * 4 + 0) * 512 + c];
        v.y = Gf[(fchk * 4 + 1) * 512 + c];
        v.z = Gf[(fchk * 4 + 2) * 512 + c];
        v.w = Gf[(fchk * 4 + 3) * 512 + c];
        *(float4*)&outb[(size_t)c * HW_ + colg_prev + fchk * 4] = v;
    }
}

// ---------------- launch ----------------------------------------------------
extern "C" void kernel_launch(void* const* d_in, const int* in_sizes, int n_in,
                              void* d_out, int out_size, void* d_ws, size_t ws_size,
                              hipStream_t stream) {
    (void)in_sizes; (void)n_in; (void)out_size; (void)ws_size;
    const float* x      = (const float*)d_in[0];
    const int*   nm_idx = (const int*)d_in[2];
    const int*   m_idx  = (const int*)d_in[3];
    float* out = (float*)d_out;
    char* ws = (char*)d_ws;

    float* inv_all = (float*)(ws + 0);              // 131072 B
    float* invM    = (float*)(ws + 131072);         // 32768 B
    float* invC    = (float*)(ws + 163840);         // 98304 B
    float* pmax    = (float*)(ws + 262144);         // 3,145,728 B [8192][48][2]
    int*   pidx    = (int*)  (ws + 3407872);        // 3,145,728 B
    float* maxc    = (float*)(ws + 6553600);        // 32768 B
    int*   bestp   = (int*)  (ws + 6586368);        // 32768 B
    unsigned int* Apk = (unsigned int*)(ws + 6619136);   // 16,777,216 B
    unsigned int* Bpk = (unsigned int*)(ws + 23396352);  // 50,331,648 B (end ~70.3 MB)
    // pack buffers are dead after k_cosm; mskn/best alias into them
    float* mskn = (float*)Apk;                      // 16 MB
    float* best = (float*)Bpk;                      // 16 MB

    hipLaunchKernelGGL(k_norms,   dim3(256),  dim3(128), 0, stream, x, inv_all);
    hipLaunchKernelGGL(k_pack,    dim3(1024), dim3(256), 0, stream, x, nm_idx, m_idx, inv_all, Apk, Bpk, invM, invC);
    hipLaunchKernelGGL(k_cosm,    dim3(1536), dim3(256), 0, stream, Apk, Bpk, invM, invC, pmax, pidx);
    hipLaunchKernelGGL(k_combine, dim3(32),   dim3(256), 0, stream, x, nm_idx, m_idx, pmax, pidx, maxc, bestp);
    hipLaunchKernelGGL(k_copy,    dim3(2048), dim3(256), 0, stream, (const float4*)x, (float4*)out);
    hipLaunchKernelGGL(k_gather,  dim3(256),  dim3(256), 0, stream, x, m_idx, inv_all, bestp, mskn, best);
    hipLaunchKernelGGL(k_scan,    dim3(8),    dim3(64),  0, stream, mskn, best, maxc, m_idx, out);
}